// Round 1
// baseline (424.874 us; speedup 1.0000x reference)
//
#include <hip/hip_runtime.h>

#define T_STEPS 256
#define B_COLS  65536u
#define GAMMA_F 0.99f

#define CHUNK   16                    // time-steps per thread
#define NCHUNK  (T_STEPS / CHUNK)     // 16 chunks per column
#define BCOL    32                    // columns per block
// block = (BCOL, NCHUNK) = 512 threads = 8 waves; wave covers 32 cols x 2 chunk-rows

// Segmented affine scan over time.
// Step i (i = T-2..0):  ret = acc*D + r ; out = (ret - v)^2 ; acc = l ? tv : ret
// As an affine map: acc -> g*acc + o, g = l?0:D, o = l?tv:r.
// Phase 1: each thread composes its 16-step chunk into (alpha, beta), data held in regs.
// Phase 1d: 16-step serial scan per column (in LDS) yields each chunk's incoming acc.
// Phase 2: exact sequential replay from registers (bit-identical to the 1-thread scan
// whenever each chunk contains >=1 reset, which holds w.p. 1 - 6^-16 per chunk).
__global__ __launch_bounds__(512, 4) void td_loss_kernel(
    const float* __restrict__ reward,
    const float* __restrict__ discount,
    const float* __restrict__ value,
    const float* __restrict__ target_value,
    const int*   __restrict__ step_type,
    const int*   __restrict__ rollout_b,
    const int*   __restrict__ train_b,
    float*       __restrict__ out)
{
    const int x  = threadIdx.x;              // column within block
    const int ch = threadIdx.y;              // chunk index (ch=15 owns i=240..255)
    const unsigned col  = blockIdx.x * BCOL + x;
    const int      hi   = ch * CHUNK + (CHUNK - 1);      // highest step in chunk
    const unsigned base = (unsigned)hi * B_COLS + col;   // element idx of step hi
    // j = 0..15  <=>  step i = hi - j  (processed in application order, high->low)

    __shared__ float s_alpha[NCHUNK][BCOL];
    __shared__ float s_beta [NCHUNK][BCOL];
    __shared__ float s_accin[NCHUNK][BCOL];

    // ---- Phase 1a: flag loads, folded into a 16-bit reset mask.
    // Three separate 16-load batches keep int register pressure low.
    unsigned mask = 0;
#pragma unroll
    for (int j = 0; j < CHUNK; ++j)
        mask |= (unsigned)(step_type[base - (unsigned)j * B_COLS] == 2) << j;
#pragma unroll
    for (int j = 0; j < CHUNK; ++j)
        mask |= (unsigned)(rollout_b[base - (unsigned)j * B_COLS] != 0) << j;
#pragma unroll
    for (int j = 0; j < CHUNK; ++j)
        mask |= (unsigned)(train_b[base - (unsigned)j * B_COLS] != 0) << j;
    // i = T-1 acts as a forced reset (acc := target_value[T-1]); out[T-1] = 0.
    if (ch == NCHUNK - 1) mask |= 1u;
    // (i = 0: reference forces b[0]=False, but the flag at i=0 only affects acc
    //  AFTER out[0] is written, and that acc is never consumed -> no special case.)

    // ---- Phase 1b: data loads (64 floats per thread, kept resident in VGPRs).
    float D[CHUNK], r[CHUNK], tv[CHUNK], v[CHUNK];
#pragma unroll
    for (int j = 0; j < CHUNK; ++j) {
        const unsigned idx  = base - (unsigned)j * B_COLS;
        // discount/reward come from row i+1; clamp at i=T-1 (value unused there)
        const unsigned idx1 = (hi - j == T_STEPS - 1) ? idx : idx + B_COLS;
        D[j]  = discount[idx1] * GAMMA_F;   // same rounding as d*GAMMA then fmaf
        r[j]  = reward[idx1];
        tv[j] = target_value[idx];
        v[j]  = value[idx];
    }

    // ---- Phase 1c: compose chunk-local affine map  acc_out = alpha*acc_in + beta.
    float alpha = 1.0f, beta = 0.0f;
#pragma unroll
    for (int j = 0; j < CHUNK; ++j) {
        const bool  l = (mask >> j) & 1u;
        const float g = l ? 0.0f : D[j];
        const float o = l ? tv[j] : r[j];
        beta  = fmaf(g, beta, o);   // identical rounding to the sequential update
        alpha *= g;                 // collapses to 0 at the first reset
    }
    s_alpha[ch][x] = alpha;
    s_beta [ch][x] = beta;
    __syncthreads();

    // ---- Phase 1d: serial scan over 16 chunk summaries, one thread per column.
    if (ch == 0) {
        float acc = 0.0f;                      // chunk 15 begins with a forced reset
#pragma unroll
        for (int k = NCHUNK - 1; k >= 0; --k) {
            s_accin[k][x] = acc;               // acc entering chunk k
            acc = fmaf(s_alpha[k][x], acc, s_beta[k][x]);
        }
    }
    __syncthreads();

    // ---- Phase 2: exact sequential replay from registers; coalesced stores.
    float acc = s_accin[ch][x];
#pragma unroll
    for (int j = 0; j < CHUNK; ++j) {
        const float ret  = fmaf(acc, D[j], r[j]);
        const bool  l    = (mask >> j) & 1u;
        acc = l ? tv[j] : ret;
        const float diff = ret - v[j];
        float o = diff * diff;
        if (hi - j == T_STEPS - 1) o = 0.0f;   // loss[T-1] = 0 (wave-uniform branch)
        out[base - (unsigned)j * B_COLS] = o;
    }
}

extern "C" void kernel_launch(void* const* d_in, const int* in_sizes, int n_in,
                              void* d_out, int out_size, void* d_ws, size_t ws_size,
                              hipStream_t stream) {
    const float* reward       = (const float*)d_in[0];
    const float* discount     = (const float*)d_in[1];
    const float* value        = (const float*)d_in[2];
    const float* target_value = (const float*)d_in[3];
    const int*   step_type    = (const int*)d_in[4];
    const int*   rollout_b    = (const int*)d_in[5];
    const int*   train_b      = (const int*)d_in[6];
    float*       out          = (float*)d_out;

    dim3 block(BCOL, NCHUNK);          // 512 threads
    dim3 grid(B_COLS / BCOL);          // 2048 blocks
    td_loss_kernel<<<grid, block, 0, stream>>>(
        reward, discount, value, target_value, step_type, rollout_b, train_b, out);
}